// Round 6
// baseline (1329.243 us; speedup 1.0000x reference)
//
#include <hip/hip_runtime.h>
#include <hip/hip_fp16.h>

// BiLSTM-CRF forward, MI355X. Round 9: k_lstm v9 = v8 + issue-early/check-late
// peer polling (T14 on the LLC atomic), per-wave redundant poll, barrier-1
// removed. Theory: v8's residual ~2900 stall cyc/step was the exposed LLC
// poll RT (first poll issued too late -> stale tag -> sleep+retry) convoyed
// through barrier 1. v9: every wave issues its own 64-lane peer load at step
// top, runs phase A while it flies, checks after; writes the peer half to LDS
// itself (redundant same-value writes, benign) and proceeds on its own
// lgkmcnt(0) — no barrier between phases A and B.

typedef unsigned int  uint32;
typedef unsigned short ushort16;
typedef unsigned long long uint64;
typedef __attribute__((ext_vector_type(8))) short  short8;   // 8 bf16 (4 VGPRs) — MFMA A/B frag
typedef __attribute__((ext_vector_type(4))) float  floatx4;  // MFMA C/D frag
typedef __attribute__((ext_vector_type(2))) _Float16 half2t;

#define BB 64
#define TT 512
#define NT (BB*TT)        // 32768 rows
#define G4 1024           // 4*H
#define NL 9

__device__ inline float bf2f(ushort16 u) {
  return __builtin_bit_cast(float, ((uint32)u) << 16);
}
__device__ inline ushort16 f2bf(float f) {  // RN-even bf16
  uint32 u = __builtin_bit_cast(uint32, f);
  u += 0x7fffu + ((u >> 16) & 1u);
  return (ushort16)(u >> 16);
}
__device__ inline float sigf(float x)  { return 1.0f / (1.0f + __expf(-x)); }
__device__ inline float tanhf_(float x){ return 1.0f - 2.0f / (1.0f + __expf(2.0f * x)); }

__device__ inline float fdot2_(uint32 w, half2t h, float acc) {
  return __builtin_amdgcn_fdot2(__builtin_bit_cast(half2t, w), h, acc, false);
}

// LDS-only workgroup barrier: orders LDS ops, lets vmcnt free-run.
// sched_barrier(0) fences both sides (rule #18: hipcc may hoist past asm).
__device__ inline void bar_lds() {
  __builtin_amdgcn_sched_barrier(0);
  asm volatile("s_waitcnt lgkmcnt(0)" ::: "memory");
  __builtin_amdgcn_s_barrier();
  __builtin_amdgcn_sched_barrier(0);
}

// ---------------- K1: seq_len ----------------
__global__ __launch_bounds__(64) void k_seqlen(const int* __restrict__ tokens,
                                               int* __restrict__ slen,
                                               float* __restrict__ out_sl) {
  const int b = blockIdx.x, lane = threadIdx.x;
  int cnt = 0;
  for (int t = lane; t < TT; t += 64) cnt += (tokens[b * TT + t] != 0) ? 1 : 0;
  #pragma unroll
  for (int off = 32; off >= 1; off >>= 1) cnt += __shfl_down(cnt, off, 64);
  if (lane == 0) { slen[b] = cnt; out_sl[b] = (float)cnt; }
}

// ---------------- K2a: embedding gather -> bf16 A matrix [NT][256] ----------------
__global__ __launch_bounds__(256) void k_embed(const int* __restrict__ tokens,
                                               const float* __restrict__ emb,
                                               ushort16* __restrict__ A) {
  const int f = blockIdx.x * 256 + threadIdx.x;  // float4 group, NT*256/4 total
  const int e = f * 4;
  const int row = e >> 8;
  const int col = e & 255;
  const int tok = tokens[row];
  const float4 v = *(const float4*)(emb + (size_t)tok * 256 + col);
  uint32 lo = (uint32)f2bf(v.x) | ((uint32)f2bf(v.y) << 16);
  uint32 hi = (uint32)f2bf(v.z) | ((uint32)f2bf(v.w) << 16);
  *(uint2*)(A + e) = make_uint2(lo, hi);
}

// ---------------- K2b: BT[c][k] = Wx_{f|b}[k][c] bf16, c in [0,2048) ----------------
__global__ __launch_bounds__(256) void k_wxprep(const float* __restrict__ Wxf,
                                                const float* __restrict__ Wxb,
                                                ushort16* __restrict__ BT) {
  const int id = blockIdx.x * 256 + threadIdx.x;   // 2048*256
  const int c = id >> 8, k = id & 255;
  const float v = (c < G4) ? Wxf[k * G4 + c] : Wxb[k * G4 + (c - G4)];
  BT[c * 256 + k] = f2bf(v);
}

// ---------------- K2c: Wh -> half2 pack, layout [k2][1024] ----------------
__global__ __launch_bounds__(256) void k_whprep(const float* __restrict__ Wh,
                                                uint32* __restrict__ W2) {
  const int id = blockIdx.x * 256 + threadIdx.x;   // 128*1024
  const int k2 = id >> 10, c = id & 1023;
  const float w0 = Wh[(2 * k2) * G4 + c];
  const float w1 = Wh[(2 * k2 + 1) * G4 + c];
  const ushort16 b0 = __builtin_bit_cast(ushort16, (_Float16)w0);
  const ushort16 b1 = __builtin_bit_cast(ushort16, (_Float16)w1);
  W2[id] = ((uint32)b1 << 16) | (uint32)b0;
}

// ---------------- K3: xg GEMM  [NT,256] @ [256,2048] -> bf16 xg_f | xg_b ----------------
__global__ __launch_bounds__(256) void k_gemm_xg(const ushort16* __restrict__ A,
                                                 const ushort16* __restrict__ BT,
                                                 const float* __restrict__ bias_f,
                                                 const float* __restrict__ bias_b,
                                                 ushort16* __restrict__ xgf,
                                                 ushort16* __restrict__ xgb) {
  __shared__ __align__(16) ushort16 As[64 * 36];
  __shared__ __align__(16) ushort16 Bs[64 * 36];
  const int m0 = blockIdx.x * 64;
  const int n0 = blockIdx.y * 64;
  const int tid = threadIdx.x;
  const int wave = tid >> 6, lane = tid & 63;
  const int lr = tid >> 2;            // staging row 0..63
  const int lc = (tid & 3) * 8;       // staging col {0,8,16,24}
  const int am = lane & 15, aq = lane >> 4;
  floatx4 acc[4];
  #pragma unroll
  for (int j = 0; j < 4; ++j) acc[j] = (floatx4){0.f, 0.f, 0.f, 0.f};

  for (int k0 = 0; k0 < 256; k0 += 32) {
    const uint4 va = *(const uint4*)(A  + ((m0 + lr) * 256 + k0 + lc));
    const uint4 vb = *(const uint4*)(BT + ((n0 + lr) * 256 + k0 + lc));
    *(uint2*)&As[lr * 36 + lc]     = make_uint2(va.x, va.y);
    *(uint2*)&As[lr * 36 + lc + 4] = make_uint2(va.z, va.w);
    *(uint2*)&Bs[lr * 36 + lc]     = make_uint2(vb.x, vb.y);
    *(uint2*)&Bs[lr * 36 + lc + 4] = make_uint2(vb.z, vb.w);
    __syncthreads();
    union { uint2 u[2]; short8 s; } fa, fb;
    fa.u[0] = *(const uint2*)&As[(wave * 16 + am) * 36 + aq * 8];
    fa.u[1] = *(const uint2*)&As[(wave * 16 + am) * 36 + aq * 8 + 4];
    #pragma unroll
    for (int j = 0; j < 4; ++j) {
      fb.u[0] = *(const uint2*)&Bs[(j * 16 + am) * 36 + aq * 8];
      fb.u[1] = *(const uint2*)&Bs[(j * 16 + am) * 36 + aq * 8 + 4];
      acc[j] = __builtin_amdgcn_mfma_f32_16x16x32_bf16(fa.s, fb.s, acc[j], 0, 0, 0);
    }
    __syncthreads();
  }
  // C/D layout (m89/m91-verified): col = lane&15, row = (lane>>4)*4 + reg
  const int orow = m0 + wave * 16 + aq * 4;
  #pragma unroll
  for (int j = 0; j < 4; ++j) {
    const int col = n0 + j * 16 + am;
    const float bv = (col < G4) ? bias_f[col] : bias_b[col - G4];
    #pragma unroll
    for (int r = 0; r < 4; ++r) {
      const float v = acc[j][r] + bv;
      const int row = orow + r;
      if (col < G4) xgf[row * G4 + col] = f2bf(v);
      else          xgb[row * G4 + (col - G4)] = f2bf(v);
    }
  }
}

// ---------------- K3b: zero the h-exchange tag buffer (per launch/replay) ----------------
__global__ __launch_bounds__(256) void k_zero(uint64* __restrict__ xh) {
  xh[blockIdx.x * 256 + threadIdx.x] = 0ull;
}

// ---------------- K4: LSTM recurrence v9 — per-wave early poll, no bar-1 ----
// Grid 256: bid -> dir=bid>>7, b=(bid>>1)&63, half=bid&1; partner = bid^1.
// 512 threads; thread tid: q=tid>>7 (gate), r=tid&127, col=q*256+half*128+r.
// wv[0..63]  = W2 rows (half*64 + i)      <- OWN-half k2 pairs (phase A)
// wv[64..127]= W2 rows ((1-half)*64 + i)  <- PEER-half k2 pairs (phase B)
// h2 LDS: slots [0,64) own pairs (local), [64,128) peer pairs (fetched).
// Poll: every wave issues its own lane-l peer-word load at step top, checks
// after phase A; writes [64,128) itself (redundant across waves, benign) and
// enters phase B on its own lgkmcnt(0). Barriers 2/3 are LDS-only (bar_lds).
__global__ __launch_bounds__(512, 2) void k_lstm(const ushort16* __restrict__ xgf,
                                                 const ushort16* __restrict__ xgb,
                                                 const uint32* __restrict__ Whf,
                                                 const uint32* __restrict__ Whb,
                                                 uint64* __restrict__ xh,
                                                 float* __restrict__ enc) {
  __shared__ __align__(16) uint32 h2[2][128];   // packed f16 h pairs, dbuf by parity
  __shared__ float gl[512];                     // transformed gate staging
  const int bid  = blockIdx.x;
  const int dir  = bid >> 7;
  const int b    = (bid >> 1) & 63;
  const int half = bid & 1;
  const int tid  = threadIdx.x;
  const int l = tid & 63;
  const int q = tid >> 7, r = tid & 127;
  const int col = q * 256 + half * 128 + r;
  const ushort16* __restrict__ xg = dir ? xgb : xgf;
  const uint32* __restrict__ W2   = dir ? Whb : Whf;
  uint64* const xmine = xh + ((size_t)bid << 7);          // [2 par][64] u64
  const uint64* const xpeer = xh + ((size_t)(bid ^ 1) << 7);

  // Weight rows, permuted own-first. Runtime base only at LOAD time;
  // every later wv index is a literal (post-unroll).
  const int ownBase  = half * 64;
  const int peerBase = 64 - ownBase;
  uint32 wv[128];
  #pragma unroll
  for (int i = 0; i < 64; ++i) wv[i]      = W2[(ownBase  + i) * 1024 + col];
  #pragma unroll
  for (int i = 0; i < 64; ++i) wv[64 + i] = W2[(peerBase + i) * 1024 + col];
  #pragma unroll
  for (int i = 0; i < 128; ++i) asm volatile("" : "+v"(wv[i]));

  if (tid < 128) { h2[0][tid] = 0u; }  // h0 = 0 (own + peer slots)
  float c_state = 0.f;                 // live in tid<128
  __syncthreads();

  const int t0 = dir ? (TT - 1) : 0;
  ushort16 xA = xg[(size_t)(b * TT + t0) * G4 + col];

#define HC(u) __builtin_bit_cast(half2t, u)
#define GR4(B) { const uint4 hq = hb[B]; \
                 a0 = fdot2_(wv[(B)*4+0], HC(hq.x), a0); \
                 a1 = fdot2_(wv[(B)*4+1], HC(hq.y), a1); \
                 a2 = fdot2_(wv[(B)*4+2], HC(hq.z), a2); \
                 a3 = fdot2_(wv[(B)*4+3], HC(hq.w), a3); }

  for (int s = 0; s < TT; ++s) {
    const int par = s & 1;
    float a0 = bf2f(xA), a1 = 0.f, a2 = 0.f, a3 = 0.f;
    if (s + 1 < TT) {       // prefetch next step's x-gate (vmcnt free-runs)
      const int t1 = dir ? (TT - 2 - s) : (s + 1);
      xA = xg[(size_t)(b * TT + t1) * G4 + col];
    }
    // ---- issue peer poll EARLY (T14): every wave, lane l -> word l ----
    const uint64* ppeer = xpeer + (par << 6) + l;
    uint64 pv_ = 0;
    if (s > 0) {
      pv_ = __hip_atomic_load(ppeer, __ATOMIC_RELAXED, __HIP_MEMORY_SCOPE_AGENT);
    }
    __builtin_amdgcn_sched_barrier(0);   // keep the load above phase A
    const uint4* hb = (const uint4*)h2[par];
    // ---- phase A: own half (slots 0..15, wv[0..63]) — overlaps poll RT ----
    GR4(0)  GR4(1)  GR4(2)  GR4(3)  GR4(4)  GR4(5)  GR4(6)  GR4(7)
    GR4(8)  GR4(9)  GR4(10) GR4(11) GR4(12) GR4(13) GR4(14) GR4(15)
    // ---- check-late; per-wave retry; redundant LDS write of peer half ----
    if (s > 0) {
      const uint32 want = (uint32)s;
      while (!__all((uint32)(pv_ >> 32) == want)) {
        __builtin_amdgcn_s_sleep(1);
        pv_ = __hip_atomic_load(ppeer, __ATOMIC_RELAXED, __HIP_MEMORY_SCOPE_AGENT);
      }
      h2[par][64 + l] = (uint32)pv_;
    }
    __builtin_amdgcn_sched_barrier(0);
    asm volatile("s_waitcnt lgkmcnt(0)" ::: "memory");   // own ds_write visible
    __builtin_amdgcn_sched_barrier(0);
    // ---- phase B: peer half (slots 16..31, wv[64..127]) — no s_barrier ----
    GR4(16) GR4(17) GR4(18) GR4(19) GR4(20) GR4(21) GR4(22) GR4(23)
    GR4(24) GR4(25) GR4(26) GR4(27) GR4(28) GR4(29) GR4(30) GR4(31)
    {
      float tv = (a0 + a1) + (a2 + a3);
      // gate nonlinearity in parallel across 512 threads (q wave-uniform)
      tv = (q == 2) ? tanhf_(tv) : sigf(tv);
      gl[tid] = tv;
    }
    bar_lds();
    if (tid < 128) {   // tail: c = F*c + I*G; h = O*tanh(c)
      const float I = gl[tid];
      const float F = gl[128 + tid];
      const float G = gl[256 + tid];
      const float O = gl[384 + tid];
      c_state = F * c_state + I * G;
      const float h = O * tanhf_(c_state);
      // pack f16 pairs; even lanes own one dword (local pair index tid>>1)
      const int hv = (int)(uint32)__builtin_bit_cast(ushort16, (_Float16)h);
      const int ho = __shfl_xor(hv, 1, 64);
      if (!(tid & 1)) {
        const uint32 pk = ((uint32)hv & 0xffffu) | ((uint32)ho << 16);
        if (s + 1 < TT) {   // publish {tag=s+1, pair} for the peer WG — ASAP
          const uint64 pv = ((uint64)(uint32)(s + 1) << 32) | (uint64)pk;
          __hip_atomic_store(xmine + ((par ^ 1) << 6) + (tid >> 1), pv,
                             __ATOMIC_RELAXED, __HIP_MEMORY_SCOPE_AGENT);
        }
        h2[par ^ 1][tid >> 1] = pk;              // own slots [0,64)
      }
      const int t = dir ? (TT - 1 - s) : s;
      enc[(size_t)(b * TT + t) * 512 + dir * 256 + half * 128 + tid] = h;
    }
    bar_lds();
  }
#undef HC
#undef GR4
}

// ---------------- K5: logits = enc @ W_dense + b ----------------
__global__ __launch_bounds__(256) void k_dense(const float* __restrict__ enc,
                                               const float* __restrict__ Wd,
                                               const float* __restrict__ bd,
                                               float* __restrict__ logits) {
  __shared__ float Wl[512 * NL];
  __shared__ float bl[NL];
  const int tid = threadIdx.x;
  for (int i = tid; i < 512 * NL; i += 256) Wl[i] = Wd[i];
  if (tid < NL) bl[tid] = bd[tid];
  __syncthreads();
  const int wave = tid >> 6, lane = tid & 63;
  const int row = blockIdx.x * 4 + wave;
  const float* er = enc + (size_t)row * 512;
  float p[NL];
  #pragma unroll
  for (int c = 0; c < NL; ++c) p[c] = 0.f;
  #pragma unroll
  for (int u = 0; u < 8; ++u) {
    const int k = u * 64 + lane;
    const float v = er[k];
    const float* wr = &Wl[k * NL];
    #pragma unroll
    for (int c = 0; c < NL; ++c) p[c] += v * wr[c];
  }
  #pragma unroll
  for (int c = 0; c < NL; ++c) {
    #pragma unroll
    for (int off = 32; off >= 1; off >>= 1) p[c] += __shfl_down(p[c], off, 64);
  }
  if (lane == 0) {
    float* orow = logits + (size_t)row * NL;
    #pragma unroll
    for (int c = 0; c < NL; ++c) orow[c] = p[c] + bl[c];
  }
}

// ---------------- K6: CRF log-likelihood ----------------
__global__ __launch_bounds__(64) void k_crf(const float* __restrict__ logits,
                                            const int* __restrict__ labels,
                                            const int* __restrict__ slen,
                                            const float* __restrict__ trans,
                                            float* __restrict__ out_ll) {
  __shared__ float tr[NL * NL];
  __shared__ float alpha[NL];
  const int b = blockIdx.x;
  const int lane = threadIdx.x;
  for (int i = lane; i < NL * NL; i += 64) tr[i] = trans[i];
  __syncthreads();
  const int len = slen[b];
  const int* tg = labels + b * TT;
  const float* lg = logits + (size_t)b * TT * NL;
  float s = 0.f;
  for (int t = lane; t < TT; t += 64)
    if (t < len) s += lg[t * NL + tg[t]];
  for (int t = lane; t < TT - 1; t += 64)
    if (t + 1 < len) s += tr[tg[t] * NL + tg[t + 1]];
  #pragma unroll
  for (int off = 32; off >= 1; off >>= 1) s += __shfl_down(s, off, 64);
  if (lane < NL) alpha[lane] = lg[lane];
  __syncthreads();
  if (lane < NL) {
    const int j = lane;
    for (int t = 1; t < TT; ++t) {
      if (t < len) {
        float av[NL];
        float m = -1e30f;
        #pragma unroll
        for (int i = 0; i < NL; ++i) { av[i] = alpha[i] + tr[i * NL + j]; m = fmaxf(m, av[i]); }
        float ss = 0.f;
        #pragma unroll
        for (int i = 0; i < NL; ++i) ss += __expf(av[i] - m);
        const float nj = m + __logf(ss) + lg[t * NL + j];
        alpha[j] = nj;
      }
    }
  }
  __syncthreads();
  if (lane == 0) {
    float m = -1e30f;
    #pragma unroll
    for (int i = 0; i < NL; ++i) m = fmaxf(m, alpha[i]);
    float ss = 0.f;
    #pragma unroll
    for (int i = 0; i < NL; ++i) ss += __expf(alpha[i] - m);
    out_ll[b] = s - (m + __logf(ss));
  }
}

extern "C" void kernel_launch(void* const* d_in, const int* in_sizes, int n_in,
                              void* d_out, int out_size, void* d_ws, size_t ws_size,
                              hipStream_t stream) {
  (void)in_sizes; (void)n_in; (void)out_size; (void)ws_size;
  const int*   tokens = (const int*)d_in[0];
  const int*   labels = (const int*)d_in[1];
  const float* emb    = (const float*)d_in[2];
  const float* Wxf    = (const float*)d_in[3];
  const float* Whf    = (const float*)d_in[4];
  const float* bf_    = (const float*)d_in[5];
  const float* Wxb    = (const float*)d_in[6];
  const float* Whb    = (const float*)d_in[7];
  const float* bb_    = (const float*)d_in[8];
  const float* Wd     = (const float*)d_in[9];
  const float* bd     = (const float*)d_in[10];
  const float* trans  = (const float*)d_in[11];
  float* out = (float*)d_out;   // [logits 294912][seq_len 64][ll 64]

  char* ws = (char*)d_ws;
  ushort16* A    = (ushort16*)(ws + 0);           // 16 MB  bf16 emb rows
  ushort16* BT   = (ushort16*)(ws + 16777216);    //  1 MB  Wx^T bf16 (2048x256)
  uint32*   W2f  = (uint32*)  (ws + 17825792);    // 512 KB Wh_f half2 [128][1024]
  uint32*   W2b  = (uint32*)  (ws + 18350080);    // 512 KB
  ushort16* xgf  = (ushort16*)(ws + 18874368);    // 64 MB  bf16 [NT][1024]
  ushort16* xgb  = (ushort16*)(ws + 85983232);    // 64 MB
  float*    enc  = (float*)   (ws + 153092096);   // 64 MB  fp32 [NT][512]
  int*      slen = (int*)     (ws + 220200960);   // 256 B
  // h-exchange buffer: 256 WG x 2 parity x 64 u64 = 256 KB.
  // Reuses the A region (dead after k_gemm_xg); k_zero resets tags before k_lstm.
  uint64*   xh   = (uint64*)  (ws + 0);

  k_seqlen<<<BB, 64, 0, stream>>>(tokens, slen, out + NT * NL);
  k_embed <<<NT * 256 / 4 / 256, 256, 0, stream>>>(tokens, emb, A);
  k_wxprep<<<2048 * 256 / 256, 256, 0, stream>>>(Wxf, Wxb, BT);
  k_whprep<<<128 * 1024 / 256, 256, 0, stream>>>(Whf, W2f);
  k_whprep<<<128 * 1024 / 256, 256, 0, stream>>>(Whb, W2b);
  k_gemm_xg<<<dim3(NT / 64, 2048 / 64), 256, 0, stream>>>(A, BT, bf_, bb_, xgf, xgb);
  k_zero  <<<128, 256, 0, stream>>>(xh);   // 32768 u64 tags -> 0 (per replay)
  k_lstm  <<<256, 512, 0, stream>>>(xgf, xgb, W2f, W2b, xh, enc);
  k_dense <<<NT / 4, 256, 0, stream>>>(enc, Wd, bd, out);
  k_crf   <<<BB, 64, 0, stream>>>(out, labels, slen, trans, out + NT * NL + BB);
}